// Round 22
// baseline (101.955 us; speedup 1.0000x reference)
//
#include <hip/hip_runtime.h>
#include <hip/hip_bf16.h>

typedef unsigned short u16;
typedef unsigned int u32;
typedef __attribute__((ext_vector_type(4))) float f32x4;
typedef __attribute__((ext_vector_type(4))) u32 u32x4;
typedef __attribute__((ext_vector_type(2))) u32 u32x2;
typedef __attribute__((ext_vector_type(8))) __bf16 bf16x8;

#define SQ 3072
#define NH 4
#define DH 32

static __device__ __forceinline__ u16 f2bf(float f) {
  return __builtin_bit_cast(u16, (__bf16)f);
}
static __device__ __forceinline__ u32 pk2(float a, float b) {
  return (u32)f2bf(a) | ((u32)f2bf(b) << 16);
}
static __device__ __forceinline__ bf16x8 ld8(const u16* p) {
  return __builtin_bit_cast(bf16x8, *reinterpret_cast<const u32x4*>(p));
}
static __device__ __forceinline__ f32x4 mfma16(bf16x8 a, bf16x8 b, f32x4 c) {
  return __builtin_amdgcn_mfma_f32_16x16x32_bf16(a, b, c, 0, 0, 0);
}
static __device__ __forceinline__ float sigm(float x) { return 1.0f / (1.0f + __expf(-x)); }
static __device__ __forceinline__ float red16(float v) {
  v += __shfl_xor(v, 1); v += __shfl_xor(v, 2);
  v += __shfl_xor(v, 4); v += __shfl_xor(v, 8);
  return v;
}

// 8-wave GEMM: A 32x128 bf16 in LDS (stride 136), B = WT[cout][k] (128x128).
static __device__ __forceinline__ void gemm8(
    const u16* a, const u16* wt, int lr, int lg, int w, f32x4 d[2]) {
  f32x4 z = {0.f, 0.f, 0.f, 0.f};
  d[0] = z; d[1] = z;
#pragma unroll
  for (int kc = 0; kc < 4; ++kc) {
    int ko = kc * 32 + lg * 8;
    bf16x8 a0 = ld8(a + lr * 136 + ko);
    bf16x8 a1 = ld8(a + (16 + lr) * 136 + ko);
    bf16x8 b0 = ld8(wt + (w * 16 + lr) * 128 + ko);
    d[0] = mfma16(a0, b0, d[0]);
    d[1] = mfma16(a1, b0, d[1]);
  }
}

struct PrepSrc { const float* p[10]; };

// Coalesced transpose: dst[m][cout][k] = W_m[k][cout], via LDS tile.
__global__ __launch_bounds__(256) void prep(PrepSrc s, u16* __restrict__ dst) {
  __shared__ float tl[32][132];
  const int mm = blockIdx.x >> 2, c = blockIdx.x & 3;
  const int tid = threadIdx.x;
  {
    const int krl = tid >> 3, col0 = (tid & 7) * 16;
    const int kr = c * 32 + krl;
    const float* src = s.p[mm] + kr * 128 + col0;
#pragma unroll
    for (int j = 0; j < 4; ++j) {
      f32x4 v = *reinterpret_cast<const f32x4*>(src + j * 4);
      tl[krl][col0 + j * 4 + 0] = v[0];
      tl[krl][col0 + j * 4 + 1] = v[1];
      tl[krl][col0 + j * 4 + 2] = v[2];
      tl[krl][col0 + j * 4 + 3] = v[3];
    }
  }
  __syncthreads();
  const int co = tid >> 1, kc0 = (tid & 1) * 16;
  u32 wbuf[8];
#pragma unroll
  for (int j = 0; j < 8; ++j)
    wbuf[j] = pk2(tl[kc0 + 2 * j][co], tl[kc0 + 2 * j + 1][co]);
  u32x4* dp = reinterpret_cast<u32x4*>(dst + mm * 16384 + co * 128 + c * 32 + kc0);
  u32x4 w0 = {wbuf[0], wbuf[1], wbuf[2], wbuf[3]};
  u32x4 w1 = {wbuf[4], wbuf[5], wbuf[6], wbuf[7]};
  dp[0] = w0; dp[1] = w1;
}

// Fused q-side + k-side row blocks (512 threads / 8 waves), 32-row blocks.
__global__ __launch_bounds__(512) void rowblocks(
    const float* __restrict__ x_q, const float* __restrict__ scq,
    const float* __restrict__ gamma_cq, const float* __restrict__ bsq,
    const float* __restrict__ bq, const float* __restrict__ bzc,
    const float* __restrict__ x_k, const float* __restrict__ sck,
    const float* __restrict__ gamma_ck, const float* __restrict__ bsk,
    const u16* __restrict__ WT, const int* __restrict__ mask_k,
    u16* __restrict__ qbf, float* __restrict__ gate, float* __restrict__ zc,
    u16* __restrict__ kbf, u16* __restrict__ vT, float* __restrict__ mkf) {
  __shared__ float xnf[32 * 132];
  __shared__ u16 a_cn[32 * 136];
  __shared__ u16 a_raw[32 * 136];
  __shared__ u16 a_xa[32 * 136];
  const int tid = threadIdx.x;
  const bool qside = blockIdx.x < 192;
  const int blk = qside ? blockIdx.x : blockIdx.x - 192;
  const float* x     = qside ? x_q : x_k;
  const float* cond  = qside ? scq : sck;
  const float* gamma = qside ? gamma_cq : gamma_ck;
  const float* bs    = qside ? bsq : bsk;
  const int rl = tid >> 4, sub = tid & 15, c0 = sub * 8;
  const size_t grow = (size_t)blk * 32 + rl;
  if (!qside && tid < 32) {
    size_t g2 = (size_t)blk * 32 + tid;
    mkf[g2] = (float)mask_k[g2] - 1.f;
  }

  {  // LN(x) -> xnf (f32)
    float xs[8];
    const float4* xr = reinterpret_cast<const float4*>(x + grow * 128 + c0);
    float4 t0 = xr[0], t1 = xr[1];
    xs[0]=t0.x; xs[1]=t0.y; xs[2]=t0.z; xs[3]=t0.w;
    xs[4]=t1.x; xs[5]=t1.y; xs[6]=t1.z; xs[7]=t1.w;
    float s = 0.f;
#pragma unroll
    for (int i = 0; i < 8; ++i) s += xs[i];
    float mean = red16(s) * (1.f / 128.f);
    float vs = 0.f;
#pragma unroll
    for (int i = 0; i < 8; ++i) { float dd = xs[i] - mean; vs += dd * dd; }
    float rstd = rsqrtf(red16(vs) * (1.f / 128.f) + 1e-5f);
    float4* xw = reinterpret_cast<float4*>(&xnf[rl * 132 + c0]);
    float4 o0, o1;
    o0.x=(xs[0]-mean)*rstd; o0.y=(xs[1]-mean)*rstd; o0.z=(xs[2]-mean)*rstd; o0.w=(xs[3]-mean)*rstd;
    o1.x=(xs[4]-mean)*rstd; o1.y=(xs[5]-mean)*rstd; o1.z=(xs[6]-mean)*rstd; o1.w=(xs[7]-mean)*rstd;
    xw[0] = o0; xw[1] = o1;
  }
  {  // LN(cond)*gamma -> a_cn; q-side raw cond -> a_raw
    float cs[8], gs[8];
    const float4* cr = reinterpret_cast<const float4*>(cond + grow * 128 + c0);
    const float4* gr = reinterpret_cast<const float4*>(gamma + c0);
    float4 c_0 = cr[0], c_1 = cr[1], g_0 = gr[0], g_1 = gr[1];
    cs[0]=c_0.x; cs[1]=c_0.y; cs[2]=c_0.z; cs[3]=c_0.w;
    cs[4]=c_1.x; cs[5]=c_1.y; cs[6]=c_1.z; cs[7]=c_1.w;
    gs[0]=g_0.x; gs[1]=g_0.y; gs[2]=g_0.z; gs[3]=g_0.w;
    gs[4]=g_1.x; gs[5]=g_1.y; gs[6]=g_1.z; gs[7]=g_1.w;
    float s = 0.f;
#pragma unroll
    for (int i = 0; i < 8; ++i) s += cs[i];
    float mean = red16(s) * (1.f / 128.f);
    float vs = 0.f;
#pragma unroll
    for (int i = 0; i < 8; ++i) { float dd = cs[i] - mean; vs += dd * dd; }
    float rstd = rsqrtf(red16(vs) * (1.f / 128.f) + 1e-5f);
    float cn[8];
#pragma unroll
    for (int i = 0; i < 8; ++i) cn[i] = (cs[i] - mean) * rstd * gs[i];
    u32x4 cw = {pk2(cn[0],cn[1]), pk2(cn[2],cn[3]), pk2(cn[4],cn[5]), pk2(cn[6],cn[7])};
    *reinterpret_cast<u32x4*>(&a_cn[rl * 136 + c0]) = cw;
    if (qside) {
      u32x4 rw = {pk2(cs[0],cs[1]), pk2(cs[2],cs[3]), pk2(cs[4],cs[5]), pk2(cs[6],cs[7])};
      *reinterpret_cast<u32x4*>(&a_raw[rl * 136 + c0]) = rw;
    }
  }
  __syncthreads();
  const int lane = tid & 63, w = tid >> 6, lr = lane & 15, lg = lane >> 4;
  const int wtbase = qside ? 0 : 5;
  f32x4 dS[2], dB[2];
  gemm8(a_cn, WT + (wtbase + 0) * 16384, lr, lg, w, dS);
  gemm8(a_cn, WT + (wtbase + 1) * 16384, lr, lg, w, dB);
  const int col = w * 16 + lr;
#pragma unroll
  for (int mt = 0; mt < 2; ++mt)
#pragma unroll
    for (int r = 0; r < 4; ++r) {
      int rowl = mt * 16 + lg * 4 + r;
      float sc = dS[mt][r] + bs[col];
      float xa = sigm(sc) * xnf[rowl * 132 + col] + dB[mt][r];
      a_xa[rowl * 136 + col] = f2bf(xa);
    }
  __syncthreads();
  if (qside) {
    f32x4 dQ[2], dG[2], dZ[2];
    gemm8(a_xa,  WT + 2 * 16384, lr, lg, w, dQ);
    gemm8(a_xa,  WT + 3 * 16384, lr, lg, w, dG);
    gemm8(a_raw, WT + 4 * 16384, lr, lg, w, dZ);
#pragma unroll
    for (int mt = 0; mt < 2; ++mt)
#pragma unroll
      for (int r = 0; r < 4; ++r) {
        int rowl = mt * 16 + lg * 4 + r;
        size_t gr = (size_t)blk * 32 + rowl;
        int b = (int)(gr >= SQ);
        int pos = (int)gr - b * SQ;
        float qv = (dQ[mt][r] + bq[col]) * 0.17677669529663687f;  // Dh^-0.5
        qbf[(((size_t)b * NH + (col >> 5)) * SQ + pos) * DH + (col & 31)] = f2bf(qv);
        gate[gr * 128 + col] = sigm(dG[mt][r]);
        zc[gr * 128 + col] = sigm(dZ[mt][r] + bzc[col]);
      }
  } else {
    f32x4 dK[2], dV[2];
    gemm8(a_xa, WT + 7 * 16384, lr, lg, w, dK);
    gemm8(a_xa, WT + 8 * 16384, lr, lg, w, dV);
    const int h = col >> 5, dd = col & 31;
#pragma unroll
    for (int mt = 0; mt < 2; ++mt)
#pragma unroll
      for (int r = 0; r < 4; ++r) {
        int rowl = mt * 16 + lg * 4 + r;
        size_t gr = (size_t)blk * 32 + rowl;
        int b = (int)(gr >= SQ);
        int pos = (int)gr - b * SQ;
        kbf[(((size_t)b * NH + h) * SQ + pos) * DH + dd] = f2bf(dK[mt][r]);
        vT[(((size_t)b * NH + h) * DH + dd) * SQ + pos] = f2bf(dV[mt][r]);
      }
  }
}

// Flash attention v22 = R21 + K-fragment prefetch one tile ahead (ping-pong
// generations, fully unrolled so t&1 is compile-time). Per-tile issue order
// after the barrier: mask(t) [QK's only wait, L1-fast] -> V(t) -> K(t+1) ->
// pair(t+1). QK never waits on L2 K-load latency; PV's V-wait is covered by
// QK+softmax; stage-write's pair-wait is covered by the whole compute phase.
__global__ __launch_bounds__(256) void attn(
    const u16* __restrict__ qbf, const u16* __restrict__ kbf, const u16* __restrict__ vT,
    const float* __restrict__ pair, const int* __restrict__ mask_q,
    const float* __restrict__ mkf, const float* __restrict__ gate,
    u16* __restrict__ wa) {
  __shared__ u16 pbuf[2][32][264];            // pair tile dbuf, bf16 (33KB)
  __shared__ __align__(16) char un[4][4608];  // union: plds [32][72] u16 / mb [32][34] f32
  const int tid = threadIdx.x, lane = tid & 63, w = tid >> 6, lr = lane & 15, lg = lane >> 4;
  const int bid = blockIdx.x;
  const int bh = bid & 7, qt = bid >> 3;  // bh in low bits -> XCD pinning
  const int b = bh >> 2, h = bh & 3;
  const int q0 = qt * 32;
  bf16x8 aq[2];
  float mqm1[2];
#pragma unroll
  for (int qg = 0; qg < 2; ++qg) {
    aq[qg] = ld8(qbf + ((size_t)bh * SQ + q0 + qg * 16 + lr) * DH + lg * 8);
    mqm1[qg] = 1e9f * ((float)mask_q[b * SQ + q0 + qg * 16 + lr] - 1.f);
  }
  float m[2] = {-1e30f, -1e30f}, lsum[2] = {0.f, 0.f};
  const f32x4 zero = {0.f, 0.f, 0.f, 0.f};
  f32x4 o[2][2];
  o[0][0] = zero; o[0][1] = zero; o[1][0] = zero; o[1][1] = zero;
  const float* prow0 = pair + ((size_t)bh * SQ + q0 + w * 8) * SQ;
  const float* mrow = mkf + b * SQ;
  const u16* krow = kbf + (size_t)bh * SQ * DH;
  u16* pw = reinterpret_cast<u16*>(un[w]);
  f32x4 pf[8];
  bf16x8 kf[2][4];  // ping-pong K generations (t&1 const after unroll)
  // prologue: pair(0) + K(0)
#pragma unroll
  for (int j = 0; j < 8; ++j)
    pf[j] = *reinterpret_cast<const f32x4*>(prow0 + (size_t)j * SQ + lane * 4);
#pragma unroll
  for (int kt = 0; kt < 4; ++kt)
    kf[0][kt] = ld8(krow + (size_t)(w * 64 + kt * 16 + lr) * DH + lg * 8);
#pragma unroll
  for (int t = 0; t < 12; ++t) {
    const int g = t & 1;
    const int bsel = t & 1;
#pragma unroll
    for (int j = 0; j < 8; ++j) {
      u32x2 pb = {pk2(pf[j][0], pf[j][1]), pk2(pf[j][2], pf[j][3])};
      *reinterpret_cast<u32x2*>(&pbuf[bsel][w * 8 + j][lane * 4]) = pb;
    }
    __syncthreads();  // tile t visible (all prior loads resident by now)
    const int kb = t * 256 + w * 64;  // this wave's 64-key chunk
    // ---- issue order: mask(t) first (QK's only wait), then V(t), K(t+1), pair(t+1)
    f32x4 mk[4];
#pragma unroll
    for (int kt = 0; kt < 4; ++kt)
      mk[kt] = *reinterpret_cast<const f32x4*>(mrow + kb + kt * 16 + lg * 4);
    bf16x8 bv[2][2];
#pragma unroll
    for (int kc = 0; kc < 2; ++kc)
#pragma unroll
      for (int hf = 0; hf < 2; ++hf)
        bv[kc][hf] = ld8(vT + ((size_t)bh * DH + hf * 16 + lr) * SQ + kb + kc * 32 + lg * 8);
    if (t < 11) {
#pragma unroll
      for (int kt = 0; kt < 4; ++kt)
        kf[g ^ 1][kt] = ld8(krow + (size_t)(kb + 256 + kt * 16 + lr) * DH + lg * 8);
#pragma unroll
      for (int j = 0; j < 8; ++j)
        pf[j] = *reinterpret_cast<const f32x4*>(prow0 + (size_t)j * SQ + (t + 1) * 256 + lane * 4);
    }
    // QK^T swapped for both q-groups: s = mfma(K[resident], Q, C=pair+maskbias)
    f32x4 s[2][4];
#pragma unroll
    for (int qg = 0; qg < 2; ++qg)
#pragma unroll
      for (int kt = 0; kt < 4; ++kt) {
        u32x2 pd = *reinterpret_cast<const u32x2*>(
            &pbuf[bsel][qg * 16 + lr][w * 64 + kt * 16 + lg * 4]);
        f32x4 pv;
        pv[0] = __builtin_bit_cast(float, (pd[0] & 0xFFFFu) << 16);
        pv[1] = __builtin_bit_cast(float, pd[0] & 0xFFFF0000u);
        pv[2] = __builtin_bit_cast(float, (pd[1] & 0xFFFFu) << 16);
        pv[3] = __builtin_bit_cast(float, pd[1] & 0xFFFF0000u);
        f32x4 c;
        c[0] = fmaf(mqm1[qg], mk[kt][0], pv[0]);
        c[1] = fmaf(mqm1[qg], mk[kt][1], pv[1]);
        c[2] = fmaf(mqm1[qg], mk[kt][2], pv[2]);
        c[3] = fmaf(mqm1[qg], mk[kt][3], pv[3]);
        s[qg][kt] = mfma16(kf[g][kt], aq[qg], c);  // D[row=k][col=q=lr]
      }
    float pm[2];
#pragma unroll
    for (int qg = 0; qg < 2; ++qg) {
      f32x4 mx = s[qg][0];
#pragma unroll
      for (int kt = 1; kt < 4; ++kt)
#pragma unroll
        for (int r = 0; r < 4; ++r) mx[r] = fmaxf(mx[r], s[qg][kt][r]);
      float p = fmaxf(fmaxf(mx[0], mx[1]), fmaxf(mx[2], mx[3]));
      p = fmaxf(p, __shfl_xor(p, 16));
      p = fmaxf(p, __shfl_xor(p, 32));
      pm[qg] = p;
    }
    if (!__all((pm[0] <= m[0] + 8.f) && (pm[1] <= m[1] + 8.f))) {
#pragma unroll
      for (int qg = 0; qg < 2; ++qg) {
        const float mn = fmaxf(m[qg], pm[qg]);
        const float alpha = __expf(m[qg] - mn);
        m[qg] = mn;
        float al[4];
#pragma unroll
        for (int r = 0; r < 4; ++r)
          al[r] = __builtin_bit_cast(
              float, __builtin_amdgcn_ds_bpermute((lg * 4 + r) << 2,
                                                  __builtin_bit_cast(int, alpha)));
#pragma unroll
        for (int hf = 0; hf < 2; ++hf)
#pragma unroll
          for (int r = 0; r < 4; ++r) o[qg][hf][r] *= al[r];
        lsum[qg] *= alpha;
      }
    }
#pragma unroll
    for (int qg = 0; qg < 2; ++qg) {
      float ps = 0.f;
#pragma unroll
      for (int kt = 0; kt < 4; ++kt) {
#pragma unroll
        for (int r = 0; r < 4; ++r) {
          float p = __expf(s[qg][kt][r] - m[qg]);
          s[qg][kt][r] = p;
          ps += p;
        }
        u32x2 pk = {pk2(s[qg][kt][0], s[qg][kt][1]), pk2(s[qg][kt][2], s[qg][kt][3])};
        *reinterpret_cast<u32x2*>(pw + (qg * 16 + lr) * 72 + kt * 16 + lg * 4) = pk;
      }
      lsum[qg] += ps;
    }
    // PV with V fragments (issued early this tile; covered by QK+softmax)
#pragma unroll
    for (int kc = 0; kc < 2; ++kc)
#pragma unroll
      for (int hf = 0; hf < 2; ++hf)
#pragma unroll
        for (int qg = 0; qg < 2; ++qg) {
          bf16x8 pa = ld8(pw + (qg * 16 + lr) * 72 + kc * 32 + lg * 8);
          o[qg][hf] = mfma16(pa, bv[kc][hf], o[qg][hf]);  // D[row=q][col=d]
        }
  }
#pragma unroll
  for (int qg = 0; qg < 2; ++qg) {
    lsum[qg] += __shfl_xor(lsum[qg], 16);
    lsum[qg] += __shfl_xor(lsum[qg], 32);
  }
  __syncthreads();  // all waves done with plds reads before overwrite
  float* mbw = reinterpret_cast<float*>(un[w]);
#pragma unroll
  for (int qg = 0; qg < 2; ++qg) {
#pragma unroll
    for (int r = 0; r < 4; ++r) {
      int row = qg * 16 + lg * 4 + r;
      mbw[row * 34 + lr] = o[qg][0][r];
      mbw[row * 34 + 16 + lr] = o[qg][1][r];
    }
    if (lane < 16) {
      mbw[(qg * 16 + lane) * 34 + 32] = m[qg];
      mbw[(qg * 16 + lane) * 34 + 33] = lsum[qg];
    }
  }
  __syncthreads();
#pragma unroll
  for (int it = 0; it < 4; ++it) {
    int q = (tid >> 5) + it * 8;  // 0..31
    int d = tid & 31;
    float mm = -1e30f;
#pragma unroll
    for (int w4 = 0; w4 < 4; ++w4)
      mm = fmaxf(mm, reinterpret_cast<const float*>(un[w4])[q * 34 + 32]);
    float ll = 0.f, oo = 0.f;
#pragma unroll
    for (int w4 = 0; w4 < 4; ++w4) {
      const float* mb4 = reinterpret_cast<const float*>(un[w4]);
      float e = __expf(mb4[q * 34 + 32] - mm);
      ll = fmaf(e, mb4[q * 34 + 33], ll);
      oo = fmaf(e, mb4[q * 34 + d], oo);
    }
    size_t gi = ((size_t)b * SQ + q0 + q) * 128 + h * 32 + d;
    wa[gi] = f2bf((oo / ll) * gate[gi]);
  }
}

// out = (wa @ Wt2) * zc — 512 threads / 8-wave GEMM split, 32-row blocks.
__global__ __launch_bounds__(512) void finalk(
    const u16* __restrict__ wa, const u16* __restrict__ WTt2,
    const float* __restrict__ zc, float* __restrict__ out) {
  __shared__ u16 awa[32 * 136];
  const int tid = threadIdx.x, rl = tid >> 4, sub = tid & 15, c0 = sub * 8;
  const size_t grow = (size_t)blockIdx.x * 32 + rl;
  *reinterpret_cast<u32x4*>(&awa[rl * 136 + c0]) =
      *reinterpret_cast<const u32x4*>(wa + grow * 128 + c0);
  __syncthreads();
  const int lane = tid & 63, w = tid >> 6, lr = lane & 15, lg = lane >> 4;
  f32x4 d[2];
  gemm8(awa, WTt2, lr, lg, w, d);
  const int col = w * 16 + lr;
#pragma unroll
  for (int mt = 0; mt < 2; ++mt)
#pragma unroll
    for (int r = 0; r < 4; ++r) {
      size_t gr = (size_t)blockIdx.x * 32 + mt * 16 + lg * 4 + r;
      out[gr * 128 + col] = d[mt][r] * zc[gr * 128 + col];
    }
}

extern "C" void kernel_launch(void* const* d_in, const int* in_sizes, int n_in,
                              void* d_out, int out_size, void* d_ws, size_t ws_size,
                              hipStream_t stream) {
  const float* x_q   = (const float*)d_in[0];
  const float* x_k   = (const float*)d_in[1];
  const int* mask_q  = (const int*)d_in[2];
  const int* mask_k  = (const int*)d_in[3];
  const float* pair  = (const float*)d_in[4];
  const float* scq   = (const float*)d_in[5];
  const float* sck   = (const float*)d_in[6];
  const float* gamma_cq = (const float*)d_in[7];
  const float* Wsq   = (const float*)d_in[8];
  const float* bsq   = (const float*)d_in[9];
  const float* Wbq   = (const float*)d_in[10];
  const float* gamma_ck = (const float*)d_in[11];
  const float* Wsk   = (const float*)d_in[12];
  const float* bsk   = (const float*)d_in[13];
  const float* Wbk   = (const float*)d_in[14];
  const float* Wq    = (const float*)d_in[15];
  const float* bq    = (const float*)d_in[16];
  const float* Wk    = (const float*)d_in[17];
  const float* Wv    = (const float*)d_in[18];
  const float* Wg    = (const float*)d_in[19];
  const float* Wt2   = (const float*)d_in[20];
  const float* Wzc   = (const float*)d_in[21];
  const float* bzc   = (const float*)d_in[22];

  char* wsb = (char*)d_ws;
  u16* WT     = (u16*)(wsb);                 // 10 x 32KB transposed bf16 weights
  u16* qbf    = (u16*)(wsb + 327680);        // [B,H,S,DH] bf16
  u16* kbf    = (u16*)(wsb + 1900544);       // [B,H,S,DH] bf16
  u16* vT     = (u16*)(wsb + 3473408);       // [B,H,DH,S] bf16
  float* gate = (float*)(wsb + 5046272);     // [B,S,C] f32
  float* zc   = (float*)(wsb + 8192000);     // [B,S,C] f32
  u16* wa     = (u16*)(wsb + 11337728);      // [B,S,C] bf16 (ends 12910592)
  float* mkf  = (float*)(wsb + 12910592);    // [B,S] f32 (mask_k - 1)
  float* out  = (float*)d_out;

  PrepSrc ps;
  ps.p[0] = Wsq; ps.p[1] = Wbq; ps.p[2] = Wq; ps.p[3] = Wg; ps.p[4] = Wzc;
  ps.p[5] = Wsk; ps.p[6] = Wbk; ps.p[7] = Wk; ps.p[8] = Wv; ps.p[9] = Wt2;

  hipLaunchKernelGGL(prep, dim3(40), dim3(256), 0, stream, ps, WT);
  hipLaunchKernelGGL(rowblocks, dim3(384), dim3(512), 0, stream,
                     x_q, scq, gamma_cq, bsq, bq, bzc,
                     x_k, sck, gamma_ck, bsk, WT, mask_k,
                     qbf, gate, zc, kbf, vT, mkf);
  hipLaunchKernelGGL(attn, dim3(8 * 96), dim3(256), 0, stream,
                     qbf, kbf, vT, pair, mask_q, mkf, gate, wa);
  hipLaunchKernelGGL(finalk, dim3(192), dim3(512), 0, stream, wa, WT + 9 * 16384, zc, out);
}

// Round 23
// 101.355 us; speedup vs baseline: 1.0059x; 1.0059x over previous
//
#include <hip/hip_runtime.h>
#include <hip/hip_bf16.h>

typedef unsigned short u16;
typedef unsigned int u32;
typedef __attribute__((ext_vector_type(4))) float f32x4;
typedef __attribute__((ext_vector_type(4))) u32 u32x4;
typedef __attribute__((ext_vector_type(2))) u32 u32x2;
typedef __attribute__((ext_vector_type(8))) __bf16 bf16x8;

#define SQ 3072
#define NH 4
#define DH 32

static __device__ __forceinline__ u16 f2bf(float f) {
  return __builtin_bit_cast(u16, (__bf16)f);
}
static __device__ __forceinline__ u32 pk2(float a, float b) {
  return (u32)f2bf(a) | ((u32)f2bf(b) << 16);
}
static __device__ __forceinline__ bf16x8 ld8(const u16* p) {
  return __builtin_bit_cast(bf16x8, *reinterpret_cast<const u32x4*>(p));
}
static __device__ __forceinline__ f32x4 mfma16(bf16x8 a, bf16x8 b, f32x4 c) {
  return __builtin_amdgcn_mfma_f32_16x16x32_bf16(a, b, c, 0, 0, 0);
}
static __device__ __forceinline__ float sigm(float x) { return 1.0f / (1.0f + __expf(-x)); }
static __device__ __forceinline__ float red16(float v) {
  v += __shfl_xor(v, 1); v += __shfl_xor(v, 2);
  v += __shfl_xor(v, 4); v += __shfl_xor(v, 8);
  return v;
}

// 8-wave GEMM: A 32x128 bf16 in LDS (stride 136), B = WT[cout][k] (128x128).
static __device__ __forceinline__ void gemm8(
    const u16* a, const u16* wt, int lr, int lg, int w, f32x4 d[2]) {
  f32x4 z = {0.f, 0.f, 0.f, 0.f};
  d[0] = z; d[1] = z;
#pragma unroll
  for (int kc = 0; kc < 4; ++kc) {
    int ko = kc * 32 + lg * 8;
    bf16x8 a0 = ld8(a + lr * 136 + ko);
    bf16x8 a1 = ld8(a + (16 + lr) * 136 + ko);
    bf16x8 b0 = ld8(wt + (w * 16 + lr) * 128 + ko);
    d[0] = mfma16(a0, b0, d[0]);
    d[1] = mfma16(a1, b0, d[1]);
  }
}

struct PrepSrc { const float* p[10]; };

// Coalesced transpose: dst[m][cout][k] = W_m[k][cout], via LDS tile.
__global__ __launch_bounds__(256) void prep(PrepSrc s, u16* __restrict__ dst) {
  __shared__ float tl[32][132];
  const int mm = blockIdx.x >> 2, c = blockIdx.x & 3;
  const int tid = threadIdx.x;
  {
    const int krl = tid >> 3, col0 = (tid & 7) * 16;
    const int kr = c * 32 + krl;
    const float* src = s.p[mm] + kr * 128 + col0;
#pragma unroll
    for (int j = 0; j < 4; ++j) {
      f32x4 v = *reinterpret_cast<const f32x4*>(src + j * 4);
      tl[krl][col0 + j * 4 + 0] = v[0];
      tl[krl][col0 + j * 4 + 1] = v[1];
      tl[krl][col0 + j * 4 + 2] = v[2];
      tl[krl][col0 + j * 4 + 3] = v[3];
    }
  }
  __syncthreads();
  const int co = tid >> 1, kc0 = (tid & 1) * 16;
  u32 wbuf[8];
#pragma unroll
  for (int j = 0; j < 8; ++j)
    wbuf[j] = pk2(tl[kc0 + 2 * j][co], tl[kc0 + 2 * j + 1][co]);
  u32x4* dp = reinterpret_cast<u32x4*>(dst + mm * 16384 + co * 128 + c * 32 + kc0);
  u32x4 w0 = {wbuf[0], wbuf[1], wbuf[2], wbuf[3]};
  u32x4 w1 = {wbuf[4], wbuf[5], wbuf[6], wbuf[7]};
  dp[0] = w0; dp[1] = w1;
}

// Fused q-side + k-side row blocks (512 threads / 8 waves), 32-row blocks.
__global__ __launch_bounds__(512) void rowblocks(
    const float* __restrict__ x_q, const float* __restrict__ scq,
    const float* __restrict__ gamma_cq, const float* __restrict__ bsq,
    const float* __restrict__ bq, const float* __restrict__ bzc,
    const float* __restrict__ x_k, const float* __restrict__ sck,
    const float* __restrict__ gamma_ck, const float* __restrict__ bsk,
    const u16* __restrict__ WT, const int* __restrict__ mask_k,
    u16* __restrict__ qbf, float* __restrict__ gate, float* __restrict__ zc,
    u16* __restrict__ kbf, u16* __restrict__ vT, float* __restrict__ mkf) {
  __shared__ float xnf[32 * 132];
  __shared__ u16 a_cn[32 * 136];
  __shared__ u16 a_raw[32 * 136];
  __shared__ u16 a_xa[32 * 136];
  const int tid = threadIdx.x;
  const bool qside = blockIdx.x < 192;
  const int blk = qside ? blockIdx.x : blockIdx.x - 192;
  const float* x     = qside ? x_q : x_k;
  const float* cond  = qside ? scq : sck;
  const float* gamma = qside ? gamma_cq : gamma_ck;
  const float* bs    = qside ? bsq : bsk;
  const int rl = tid >> 4, sub = tid & 15, c0 = sub * 8;
  const size_t grow = (size_t)blk * 32 + rl;
  if (!qside && tid < 32) {
    size_t g2 = (size_t)blk * 32 + tid;
    mkf[g2] = (float)mask_k[g2] - 1.f;
  }

  {  // LN(x) -> xnf (f32)
    float xs[8];
    const float4* xr = reinterpret_cast<const float4*>(x + grow * 128 + c0);
    float4 t0 = xr[0], t1 = xr[1];
    xs[0]=t0.x; xs[1]=t0.y; xs[2]=t0.z; xs[3]=t0.w;
    xs[4]=t1.x; xs[5]=t1.y; xs[6]=t1.z; xs[7]=t1.w;
    float s = 0.f;
#pragma unroll
    for (int i = 0; i < 8; ++i) s += xs[i];
    float mean = red16(s) * (1.f / 128.f);
    float vs = 0.f;
#pragma unroll
    for (int i = 0; i < 8; ++i) { float dd = xs[i] - mean; vs += dd * dd; }
    float rstd = rsqrtf(red16(vs) * (1.f / 128.f) + 1e-5f);
    float4* xw = reinterpret_cast<float4*>(&xnf[rl * 132 + c0]);
    float4 o0, o1;
    o0.x=(xs[0]-mean)*rstd; o0.y=(xs[1]-mean)*rstd; o0.z=(xs[2]-mean)*rstd; o0.w=(xs[3]-mean)*rstd;
    o1.x=(xs[4]-mean)*rstd; o1.y=(xs[5]-mean)*rstd; o1.z=(xs[6]-mean)*rstd; o1.w=(xs[7]-mean)*rstd;
    xw[0] = o0; xw[1] = o1;
  }
  {  // LN(cond)*gamma -> a_cn; q-side raw cond -> a_raw
    float cs[8], gs[8];
    const float4* cr = reinterpret_cast<const float4*>(cond + grow * 128 + c0);
    const float4* gr = reinterpret_cast<const float4*>(gamma + c0);
    float4 c_0 = cr[0], c_1 = cr[1], g_0 = gr[0], g_1 = gr[1];
    cs[0]=c_0.x; cs[1]=c_0.y; cs[2]=c_0.z; cs[3]=c_0.w;
    cs[4]=c_1.x; cs[5]=c_1.y; cs[6]=c_1.z; cs[7]=c_1.w;
    gs[0]=g_0.x; gs[1]=g_0.y; gs[2]=g_0.z; gs[3]=g_0.w;
    gs[4]=g_1.x; gs[5]=g_1.y; gs[6]=g_1.z; gs[7]=g_1.w;
    float s = 0.f;
#pragma unroll
    for (int i = 0; i < 8; ++i) s += cs[i];
    float mean = red16(s) * (1.f / 128.f);
    float vs = 0.f;
#pragma unroll
    for (int i = 0; i < 8; ++i) { float dd = cs[i] - mean; vs += dd * dd; }
    float rstd = rsqrtf(red16(vs) * (1.f / 128.f) + 1e-5f);
    float cn[8];
#pragma unroll
    for (int i = 0; i < 8; ++i) cn[i] = (cs[i] - mean) * rstd * gs[i];
    u32x4 cw = {pk2(cn[0],cn[1]), pk2(cn[2],cn[3]), pk2(cn[4],cn[5]), pk2(cn[6],cn[7])};
    *reinterpret_cast<u32x4*>(&a_cn[rl * 136 + c0]) = cw;
    if (qside) {
      u32x4 rw = {pk2(cs[0],cs[1]), pk2(cs[2],cs[3]), pk2(cs[4],cs[5]), pk2(cs[6],cs[7])};
      *reinterpret_cast<u32x4*>(&a_raw[rl * 136 + c0]) = rw;
    }
  }
  __syncthreads();
  const int lane = tid & 63, w = tid >> 6, lr = lane & 15, lg = lane >> 4;
  const int wtbase = qside ? 0 : 5;
  f32x4 dS[2], dB[2];
  gemm8(a_cn, WT + (wtbase + 0) * 16384, lr, lg, w, dS);
  gemm8(a_cn, WT + (wtbase + 1) * 16384, lr, lg, w, dB);
  const int col = w * 16 + lr;
#pragma unroll
  for (int mt = 0; mt < 2; ++mt)
#pragma unroll
    for (int r = 0; r < 4; ++r) {
      int rowl = mt * 16 + lg * 4 + r;
      float sc = dS[mt][r] + bs[col];
      float xa = sigm(sc) * xnf[rowl * 132 + col] + dB[mt][r];
      a_xa[rowl * 136 + col] = f2bf(xa);
    }
  __syncthreads();
  if (qside) {
    f32x4 dQ[2], dG[2], dZ[2];
    gemm8(a_xa,  WT + 2 * 16384, lr, lg, w, dQ);
    gemm8(a_xa,  WT + 3 * 16384, lr, lg, w, dG);
    gemm8(a_raw, WT + 4 * 16384, lr, lg, w, dZ);
#pragma unroll
    for (int mt = 0; mt < 2; ++mt)
#pragma unroll
      for (int r = 0; r < 4; ++r) {
        int rowl = mt * 16 + lg * 4 + r;
        size_t gr = (size_t)blk * 32 + rowl;
        int b = (int)(gr >= SQ);
        int pos = (int)gr - b * SQ;
        float qv = (dQ[mt][r] + bq[col]) * 0.17677669529663687f;  // Dh^-0.5
        qbf[(((size_t)b * NH + (col >> 5)) * SQ + pos) * DH + (col & 31)] = f2bf(qv);
        gate[gr * 128 + col] = sigm(dG[mt][r]);
        zc[gr * 128 + col] = sigm(dZ[mt][r] + bzc[col]);
      }
  } else {
    f32x4 dK[2], dV[2];
    gemm8(a_xa, WT + 7 * 16384, lr, lg, w, dK);
    gemm8(a_xa, WT + 8 * 16384, lr, lg, w, dV);
    const int h = col >> 5, dd = col & 31;
#pragma unroll
    for (int mt = 0; mt < 2; ++mt)
#pragma unroll
      for (int r = 0; r < 4; ++r) {
        int rowl = mt * 16 + lg * 4 + r;
        size_t gr = (size_t)blk * 32 + rowl;
        int b = (int)(gr >= SQ);
        int pos = (int)gr - b * SQ;
        kbf[(((size_t)b * NH + h) * SQ + pos) * DH + dd] = f2bf(dK[mt][r]);
        vT[(((size_t)b * NH + h) * DH + dd) * SQ + pos] = f2bf(dV[mt][r]);
      }
  }
}

// Flash attention (R21 best): 32 q-rows/block, 2 q-groups per wave, K/V loaded
// once per tile (shared by both groups), vmem FIFO-ordered: K/mask/V first,
// pair prefetch LAST so PV waits only vmcnt(8) and pair loads stay in flight
// under the whole compute phase. Pair staged bf16; swapped-operand MFMA core
// with pair+mask folded into C; defer-max; 4-wave in-block k merge.
__global__ __launch_bounds__(256) void attn(
    const u16* __restrict__ qbf, const u16* __restrict__ kbf, const u16* __restrict__ vT,
    const float* __restrict__ pair, const int* __restrict__ mask_q,
    const float* __restrict__ mkf, const float* __restrict__ gate,
    u16* __restrict__ wa) {
  __shared__ u16 pbuf[2][32][264];            // pair tile dbuf, bf16 (33KB)
  __shared__ __align__(16) char un[4][4608];  // union: plds [32][72] u16 / mb [32][34] f32
  const int tid = threadIdx.x, lane = tid & 63, w = tid >> 6, lr = lane & 15, lg = lane >> 4;
  const int bid = blockIdx.x;
  const int bh = bid & 7, qt = bid >> 3;  // bh in low bits -> XCD pinning
  const int b = bh >> 2, h = bh & 3;
  const int q0 = qt * 32;
  bf16x8 aq[2];
  float mqm1[2];
#pragma unroll
  for (int qg = 0; qg < 2; ++qg) {
    aq[qg] = ld8(qbf + ((size_t)bh * SQ + q0 + qg * 16 + lr) * DH + lg * 8);
    mqm1[qg] = 1e9f * ((float)mask_q[b * SQ + q0 + qg * 16 + lr] - 1.f);
  }
  float m[2] = {-1e30f, -1e30f}, lsum[2] = {0.f, 0.f};
  const f32x4 zero = {0.f, 0.f, 0.f, 0.f};
  f32x4 o[2][2];
  o[0][0] = zero; o[0][1] = zero; o[1][0] = zero; o[1][1] = zero;
  const float* prow0 = pair + ((size_t)bh * SQ + q0 + w * 8) * SQ;
  const float* mrow = mkf + b * SQ;
  u16* pw = reinterpret_cast<u16*>(un[w]);
  f32x4 pf[8];
#pragma unroll
  for (int j = 0; j < 8; ++j)
    pf[j] = *reinterpret_cast<const f32x4*>(prow0 + (size_t)j * SQ + lane * 4);
  for (int t = 0; t < 12; ++t) {
    const int bsel = t & 1;
#pragma unroll
    for (int j = 0; j < 8; ++j) {
      u32x2 pb = {pk2(pf[j][0], pf[j][1]), pk2(pf[j][2], pf[j][3])};
      *reinterpret_cast<u32x2*>(&pbuf[bsel][w * 8 + j][lane * 4]) = pb;
    }
    __syncthreads();  // tile t visible to all waves (drains all vmem)
    const int kb = t * 256 + w * 64;  // this wave's 64-key chunk
    // ---- ISSUE ORDER: K, mask, V FIRST (oldest in vmcnt FIFO) ----
    bf16x8 kf[4];
    f32x4 mk[4];
#pragma unroll
    for (int kt = 0; kt < 4; ++kt) {
      kf[kt] = ld8(kbf + ((size_t)bh * SQ + kb + kt * 16 + lr) * DH + lg * 8);
      mk[kt] = *reinterpret_cast<const f32x4*>(mrow + kb + kt * 16 + lg * 4);
    }
    bf16x8 bv[2][2];
#pragma unroll
    for (int kc = 0; kc < 2; ++kc)
#pragma unroll
      for (int hf = 0; hf < 2; ++hf)
        bv[kc][hf] = ld8(vT + ((size_t)bh * DH + hf * 16 + lr) * SQ + kb + kc * 32 + lg * 8);
    // ---- pair prefetch for t+1 issued LAST (stays in flight under compute) ----
    if (t < 11) {
#pragma unroll
      for (int j = 0; j < 8; ++j)
        pf[j] = *reinterpret_cast<const f32x4*>(prow0 + (size_t)j * SQ + (t + 1) * 256 + lane * 4);
    }
    // QK^T swapped for both q-groups: s = mfma(K, Q, C=pair+maskbias)
    f32x4 s[2][4];
#pragma unroll
    for (int qg = 0; qg < 2; ++qg)
#pragma unroll
      for (int kt = 0; kt < 4; ++kt) {
        u32x2 pd = *reinterpret_cast<const u32x2*>(
            &pbuf[bsel][qg * 16 + lr][w * 64 + kt * 16 + lg * 4]);
        f32x4 pv;
        pv[0] = __builtin_bit_cast(float, (pd[0] & 0xFFFFu) << 16);
        pv[1] = __builtin_bit_cast(float, pd[0] & 0xFFFF0000u);
        pv[2] = __builtin_bit_cast(float, (pd[1] & 0xFFFFu) << 16);
        pv[3] = __builtin_bit_cast(float, pd[1] & 0xFFFF0000u);
        f32x4 c;
        c[0] = fmaf(mqm1[qg], mk[kt][0], pv[0]);
        c[1] = fmaf(mqm1[qg], mk[kt][1], pv[1]);
        c[2] = fmaf(mqm1[qg], mk[kt][2], pv[2]);
        c[3] = fmaf(mqm1[qg], mk[kt][3], pv[3]);
        s[qg][kt] = mfma16(kf[kt], aq[qg], c);  // D[row=k][col=q=lr]
      }
    float pm[2];
#pragma unroll
    for (int qg = 0; qg < 2; ++qg) {
      f32x4 mx = s[qg][0];
#pragma unroll
      for (int kt = 1; kt < 4; ++kt)
#pragma unroll
        for (int r = 0; r < 4; ++r) mx[r] = fmaxf(mx[r], s[qg][kt][r]);
      float p = fmaxf(fmaxf(mx[0], mx[1]), fmaxf(mx[2], mx[3]));
      p = fmaxf(p, __shfl_xor(p, 16));
      p = fmaxf(p, __shfl_xor(p, 32));
      pm[qg] = p;
    }
    if (!__all((pm[0] <= m[0] + 8.f) && (pm[1] <= m[1] + 8.f))) {
#pragma unroll
      for (int qg = 0; qg < 2; ++qg) {
        const float mn = fmaxf(m[qg], pm[qg]);
        const float alpha = __expf(m[qg] - mn);
        m[qg] = mn;
        float al[4];
#pragma unroll
        for (int r = 0; r < 4; ++r)
          al[r] = __builtin_bit_cast(
              float, __builtin_amdgcn_ds_bpermute((lg * 4 + r) << 2,
                                                  __builtin_bit_cast(int, alpha)));
#pragma unroll
        for (int hf = 0; hf < 2; ++hf)
#pragma unroll
          for (int r = 0; r < 4; ++r) o[qg][hf][r] *= al[r];
        lsum[qg] *= alpha;
      }
    }
#pragma unroll
    for (int qg = 0; qg < 2; ++qg) {
      float ps = 0.f;
#pragma unroll
      for (int kt = 0; kt < 4; ++kt) {
#pragma unroll
        for (int r = 0; r < 4; ++r) {
          float p = __expf(s[qg][kt][r] - m[qg]);
          s[qg][kt][r] = p;
          ps += p;
        }
        u32x2 pk = {pk2(s[qg][kt][0], s[qg][kt][1]), pk2(s[qg][kt][2], s[qg][kt][3])};
        *reinterpret_cast<u32x2*>(pw + (qg * 16 + lr) * 72 + kt * 16 + lg * 4) = pk;
      }
      lsum[qg] += ps;
    }
    // PV with pre-loaded V fragments (no vmem wait on the pair queue)
#pragma unroll
    for (int kc = 0; kc < 2; ++kc)
#pragma unroll
      for (int hf = 0; hf < 2; ++hf)
#pragma unroll
        for (int qg = 0; qg < 2; ++qg) {
          bf16x8 pa = ld8(pw + (qg * 16 + lr) * 72 + kc * 32 + lg * 8);
          o[qg][hf] = mfma16(pa, bv[kc][hf], o[qg][hf]);  // D[row=q][col=d]
        }
  }
#pragma unroll
  for (int qg = 0; qg < 2; ++qg) {
    lsum[qg] += __shfl_xor(lsum[qg], 16);
    lsum[qg] += __shfl_xor(lsum[qg], 32);
  }
  __syncthreads();  // all waves done with plds reads before overwrite
  float* mbw = reinterpret_cast<float*>(un[w]);
#pragma unroll
  for (int qg = 0; qg < 2; ++qg) {
#pragma unroll
    for (int r = 0; r < 4; ++r) {
      int row = qg * 16 + lg * 4 + r;
      mbw[row * 34 + lr] = o[qg][0][r];
      mbw[row * 34 + 16 + lr] = o[qg][1][r];
    }
    if (lane < 16) {
      mbw[(qg * 16 + lane) * 34 + 32] = m[qg];
      mbw[(qg * 16 + lane) * 34 + 33] = lsum[qg];
    }
  }
  __syncthreads();
#pragma unroll
  for (int it = 0; it < 4; ++it) {
    int q = (tid >> 5) + it * 8;  // 0..31
    int d = tid & 31;
    float mm = -1e30f;
#pragma unroll
    for (int w4 = 0; w4 < 4; ++w4)
      mm = fmaxf(mm, reinterpret_cast<const float*>(un[w4])[q * 34 + 32]);
    float ll = 0.f, oo = 0.f;
#pragma unroll
    for (int w4 = 0; w4 < 4; ++w4) {
      const float* mb4 = reinterpret_cast<const float*>(un[w4]);
      float e = __expf(mb4[q * 34 + 32] - mm);
      ll = fmaf(e, mb4[q * 34 + 33], ll);
      oo = fmaf(e, mb4[q * 34 + d], oo);
    }
    size_t gi = ((size_t)b * SQ + q0 + q) * 128 + h * 32 + d;
    wa[gi] = f2bf((oo / ll) * gate[gi]);
  }
}

// out = (wa @ Wt2) * zc — 512 threads / 8-wave GEMM split, 32-row blocks.
__global__ __launch_bounds__(512) void finalk(
    const u16* __restrict__ wa, const u16* __restrict__ WTt2,
    const float* __restrict__ zc, float* __restrict__ out) {
  __shared__ u16 awa[32 * 136];
  const int tid = threadIdx.x, rl = tid >> 4, sub = tid & 15, c0 = sub * 8;
  const size_t grow = (size_t)blockIdx.x * 32 + rl;
  *reinterpret_cast<u32x4*>(&awa[rl * 136 + c0]) =
      *reinterpret_cast<const u32x4*>(wa + grow * 128 + c0);
  __syncthreads();
  const int lane = tid & 63, w = tid >> 6, lr = lane & 15, lg = lane >> 4;
  f32x4 d[2];
  gemm8(awa, WTt2, lr, lg, w, d);
  const int col = w * 16 + lr;
#pragma unroll
  for (int mt = 0; mt < 2; ++mt)
#pragma unroll
    for (int r = 0; r < 4; ++r) {
      size_t gr = (size_t)blockIdx.x * 32 + mt * 16 + lg * 4 + r;
      out[gr * 128 + col] = d[mt][r] * zc[gr * 128 + col];
    }
}

extern "C" void kernel_launch(void* const* d_in, const int* in_sizes, int n_in,
                              void* d_out, int out_size, void* d_ws, size_t ws_size,
                              hipStream_t stream) {
  const float* x_q   = (const float*)d_in[0];
  const float* x_k   = (const float*)d_in[1];
  const int* mask_q  = (const int*)d_in[2];
  const int* mask_k  = (const int*)d_in[3];
  const float* pair  = (const float*)d_in[4];
  const float* scq   = (const float*)d_in[5];
  const float* sck   = (const float*)d_in[6];
  const float* gamma_cq = (const float*)d_in[7];
  const float* Wsq   = (const float*)d_in[8];
  const float* bsq   = (const float*)d_in[9];
  const float* Wbq   = (const float*)d_in[10];
  const float* gamma_ck = (const float*)d_in[11];
  const float* Wsk   = (const float*)d_in[12];
  const float* bsk   = (const float*)d_in[13];
  const float* Wbk   = (const float*)d_in[14];
  const float* Wq    = (const float*)d_in[15];
  const float* bq    = (const float*)d_in[16];
  const float* Wk    = (const float*)d_in[17];
  const float* Wv    = (const float*)d_in[18];
  const float* Wg    = (const float*)d_in[19];
  const float* Wt2   = (const float*)d_in[20];
  const float* Wzc   = (const float*)d_in[21];
  const float* bzc   = (const float*)d_in[22];

  char* wsb = (char*)d_ws;
  u16* WT     = (u16*)(wsb);                 // 10 x 32KB transposed bf16 weights
  u16* qbf    = (u16*)(wsb + 327680);        // [B,H,S,DH] bf16
  u16* kbf    = (u16*)(wsb + 1900544);       // [B,H,S,DH] bf16
  u16* vT     = (u16*)(wsb + 3473408);       // [B,H,DH,S] bf16
  float* gate = (float*)(wsb + 5046272);     // [B,S,C] f32
  float* zc   = (float*)(wsb + 8192000);     // [B,S,C] f32
  u16* wa     = (u16*)(wsb + 11337728);      // [B,S,C] bf16 (ends 12910592)
  float* mkf  = (float*)(wsb + 12910592);    // [B,S] f32 (mask_k - 1)
  float* out  = (float*)d_out;

  PrepSrc ps;
  ps.p[0] = Wsq; ps.p[1] = Wbq; ps.p[2] = Wq; ps.p[3] = Wg; ps.p[4] = Wzc;
  ps.p[5] = Wsk; ps.p[6] = Wbk; ps.p[7] = Wk; ps.p[8] = Wv; ps.p[9] = Wt2;

  hipLaunchKernelGGL(prep, dim3(40), dim3(256), 0, stream, ps, WT);
  hipLaunchKernelGGL(rowblocks, dim3(384), dim3(512), 0, stream,
                     x_q, scq, gamma_cq, bsq, bq, bzc,
                     x_k, sck, gamma_ck, bsk, WT, mask_k,
                     qbf, gate, zc, kbf, vT, mkf);
  hipLaunchKernelGGL(attn, dim3(8 * 96), dim3(256), 0, stream,
                     qbf, kbf, vT, pair, mask_q, mkf, gate, wa);
  hipLaunchKernelGGL(finalk, dim3(192), dim3(512), 0, stream, wa, WT + 9 * 16384, zc, out);
}